// Round 1
// 81.621 us; speedup vs baseline: 1.0095x; 1.0095x over previous
//
#include <hip/hip_runtime.h>

#define NPARAMS 21      // 2*DEPTH+1 phases
#define INV_2PI 0.15915494309189535f
#define INV_PI  0.3183098861837907f

typedef float v2f __attribute__((ext_vector_type(2)));
typedef float v4f __attribute__((ext_vector_type(4)));

// Hardware sin/cos take REVOLUTIONS; v_fract first (exact: integer revolutions drop).
__device__ __forceinline__ float sin_rev(float rev) {
    return __builtin_amdgcn_sinf(__builtin_amdgcn_fractf(rev));
}
__device__ __forceinline__ float cos_rev(float rev) {
    return __builtin_amdgcn_cosf(__builtin_amdgcn_fractf(rev));
}

// ---------------------------------------------------------------------------
// Single fused kernel.
//
// Math: Re(U00(x)) is a trig polynomial of degree 10 in u = 2x:
//   g(u) = P0 + sum_{j=1..10} Pj cos(j u) + Qj sin(j u)
// Each block redundantly recovers P/Q: lanes 0..20 run the exact SU(2)
// recurrence at samples u_t = 2*pi*t/21, then invert with the exact 21-point
// real DFT into LDS (~300 serial ops, hidden by resident blocks/CU).
//
// This revision: the Chebyshev double-angle cascade and the P/Q accumulations
// are expressed as float2 packed ops so the compiler can emit v_pk_fma_f32:
//   (c_{k+1}, s_{k+1}) = 2*c1*(c_k, s_k) - (c_{k-1}, s_{k-1})
//   (aP, aQ)          += (P_k, Q_k) * (c_k, s_k)
// Identical fma chains / ordering to the scalar version -> bitwise-identical
// results, ~half the VALU instruction count per element.
// ---------------------------------------------------------------------------
__global__ __launch_bounds__(256) void qsp_fused_kernel(
    const float* __restrict__ x,
    const float* __restrict__ qsp,
    const float* __restrict__ alphas,
    float* __restrict__ out,
    int n)
{
    __shared__ float g[NPARAMS];
    __shared__ float coef[NPARAMS];
    const int t = threadIdx.x;

    if (t < NPARAMS) {
        // x_t = pi*t/21  ->  revolutions = t/42
        const float rev_x = (float)t * (1.0f / 42.0f);
        const float c = cos_rev(rev_x);
        const float s = sin_rev(rev_x);

        // M = [[a, b], [-conj(b), conj(a)]], start M = S(phi_0)
        float pr = qsp[0] * INV_2PI;
        float ar = cos_rev(pr), ai = sin_rev(pr);
        float br = 0.0f, bi = 0.0f;

        for (int k = 1; k < NPARAMS; ++k) {
            const float pk = qsp[k] * INV_2PI;
            const float cp = cos_rev(pk);
            const float sp = sin_rev(pk);
            const float t1r = c * ar - s * bi;
            const float t1i = c * ai + s * br;
            const float t2r = c * br - s * ai;
            const float t2i = c * bi + s * ar;
            ar = cp * t1r - sp * t1i;
            ai = cp * t1i + sp * t1r;
            br = cp * t2r + sp * t2i;
            bi = cp * t2i - sp * t2r;
        }
        g[t] = ar;   // Re(U00) at sample t
    }
    __syncthreads();

    if (t < NPARAMS) {
        float acc = 0.0f;
        if (t == 0) {
            for (int i = 0; i < NPARAMS; ++i) acc += g[i];
            acc *= (1.0f / 21.0f);
        } else if (t <= 10) {                       // Pj
            for (int i = 0; i < NPARAMS; ++i)
                acc += g[i] * cos_rev((float)(t * i) * (1.0f / 21.0f));
            acc *= (2.0f / 21.0f);
        } else {                                    // Qj, j = t-10
            const int j = t - 10;
            for (int i = 0; i < NPARAMS; ++i)
                acc += g[i] * sin_rev((float)(j * i) * (1.0f / 21.0f));
            acc *= (2.0f / 21.0f);
        }
        coef[t] = acc;
    }
    __syncthreads();

    // Broadcast LDS reads (all lanes same address -> conflict-free).
    const float P0 = coef[0];
    const v2f pq1  = {coef[1],  coef[11]};
    const v2f pq2  = {coef[2],  coef[12]};
    const v2f pq3  = {coef[3],  coef[13]};
    const v2f pq4  = {coef[4],  coef[14]};
    const v2f pq5  = {coef[5],  coef[15]};
    const v2f pq6  = {coef[6],  coef[16]};
    const v2f pq7  = {coef[7],  coef[17]};
    const v2f pq8  = {coef[8],  coef[18]};
    const v2f pq9  = {coef[9],  coef[19]};
    const v2f pq10 = {coef[10], coef[20]};

    const int base = (blockIdx.x * blockDim.x + t) * 8;
    if (base >= n) return;

    auto eval1 = [&](float xv) -> float {
        const float f  = __builtin_amdgcn_fractf(xv * INV_PI);   // u=2x in revs
        const float s1 = __builtin_amdgcn_sinf(f);
        const float c1 = __builtin_amdgcn_cosf(f);
        const float tc = c1 + c1;
        const v2f tcv = {tc, tc};

        v2f csm = {1.0f, 0.0f};   // (c_{k-1}, s_{k-1})
        v2f cs  = {c1,  s1};      // (c_k, s_k)
        v2f acc = {P0,  0.0f};    // (aP, aQ)
        v2f nx;

        acc = pq1 * cs + acc;
        nx = tcv * cs - csm; csm = cs; cs = nx;  acc = pq2  * cs + acc;
        nx = tcv * cs - csm; csm = cs; cs = nx;  acc = pq3  * cs + acc;
        nx = tcv * cs - csm; csm = cs; cs = nx;  acc = pq4  * cs + acc;
        nx = tcv * cs - csm; csm = cs; cs = nx;  acc = pq5  * cs + acc;
        nx = tcv * cs - csm; csm = cs; cs = nx;  acc = pq6  * cs + acc;
        nx = tcv * cs - csm; csm = cs; cs = nx;  acc = pq7  * cs + acc;
        nx = tcv * cs - csm; csm = cs; cs = nx;  acc = pq8  * cs + acc;
        nx = tcv * cs - csm; csm = cs; cs = nx;  acc = pq9  * cs + acc;
        nx = tcv * cs - csm; csm = cs; cs = nx;  acc = pq10 * cs + acc;

        return acc.x + acc.y;
    };

    const v4f* xp = reinterpret_cast<const v4f*>(x + base);
    const v4f* ap = reinterpret_cast<const v4f*>(alphas + base);
    const v4f xa = xp[0], xb = xp[1];
    const v4f aa = ap[0], ab = ap[1];

    v4f oa, ob;
    oa.x = aa.x * eval1(xa.x);
    oa.y = aa.y * eval1(xa.y);
    oa.z = aa.z * eval1(xa.z);
    oa.w = aa.w * eval1(xa.w);
    ob.x = ab.x * eval1(xb.x);
    ob.y = ab.y * eval1(xb.y);
    ob.z = ab.z * eval1(xb.z);
    ob.w = ab.w * eval1(xb.w);

    v4f* op = reinterpret_cast<v4f*>(out + base);
    __builtin_nontemporal_store(oa, op);
    __builtin_nontemporal_store(ob, op + 1);
}

extern "C" void kernel_launch(void* const* d_in, const int* in_sizes, int n_in,
                              void* d_out, int out_size, void* d_ws, size_t ws_size,
                              hipStream_t stream)
{
    const float* x      = (const float*)d_in[0];
    const float* qsp    = (const float*)d_in[1];
    const float* alphas = (const float*)d_in[2];
    float* out          = (float*)d_out;

    const int n = in_sizes[0];   // 4,000,000 (divisible by 8)

    const int threads  = 256;
    const int nthreads = (n + 7) / 8;
    const int blocks   = (nthreads + threads - 1) / threads;
    qsp_fused_kernel<<<blocks, threads, 0, stream>>>(x, qsp, alphas, out, n);
}